// Round 2
// baseline (2539.177 us; speedup 1.0000x reference)
//
#include <hip/hip_runtime.h>

// Problem constants (fixed by the reference)
#define BB 32
#define DD 64
#define TT 4096
#define KK 1024

// argmin_k ||x - w_k||^2  ==  argmax_k (x . w_k - 0.5*||w_k||^2)
// One thread per point (b,t). fp32 fast pass tracks top-2; near-ties
// (gap <= EPS) are resolved with an exact fp64 re-scan so our argmin
// equals the true (infinite-precision) argmin everywhere.
__global__ __launch_bounds__(256, 2) void vq_argmin_kernel(
    const float* __restrict__ x,       // [B, D, T]
    const float* __restrict__ weight,  // [K, D]
    float* __restrict__ out)           // quantized [B,D,T] then indices [B,T] (as float)
{
    __shared__ float s_wn[KK];  // -0.5 * ||w_k||^2

    const int tid = threadIdx.x;
    const int blk = blockIdx.x;          // 512 blocks = 32 b * 16 tiles
    const int b   = blk >> 4;
    const int t   = ((blk & 15) << 8) + tid;

    // Precompute -0.5*||w_k||^2 into LDS (each thread handles 4 codes).
    for (int i = 0; i < 4; ++i) {
        const int k = (tid << 2) + i;
        const float4* wp = (const float4*)(weight + k * DD);
        float s = 0.f;
        #pragma unroll
        for (int j = 0; j < DD / 4; ++j) {
            float4 v = wp[j];
            s += v.x * v.x + v.y * v.y + v.z * v.z + v.w * v.w;
        }
        s_wn[k] = -0.5f * s;
    }
    __syncthreads();

    // Load this thread's point into registers (coalesced across lanes).
    float xr[DD];
    const float* xp = x + (size_t)b * DD * TT + t;
    #pragma unroll
    for (int d = 0; d < DD; ++d) xr[d] = xp[(size_t)d * TT];

    // fp32 pass: track best and second-best scores.
    float s1 = -1e30f, s2 = -1e30f;
    int   k1 = 0;
    for (int k = 0; k < KK; ++k) {
        const float* wk = weight + k * DD;
        // 4 independent accumulator chains (FMA latency 4cy vs issue 2cy).
        float a0 = s_wn[k], a1 = 0.f, a2 = 0.f, a3 = 0.f;
        #pragma unroll
        for (int d = 0; d < DD; d += 4) {
            a0 = fmaf(xr[d + 0], wk[d + 0], a0);
            a1 = fmaf(xr[d + 1], wk[d + 1], a1);
            a2 = fmaf(xr[d + 2], wk[d + 2], a2);
            a3 = fmaf(xr[d + 3], wk[d + 3], a3);
        }
        const float s = (a0 + a1) + (a2 + a3);
        if (s > s1)      { s2 = s1; s1 = s; k1 = k; }  // strict >: first occurrence wins
        else if (s > s2) { s2 = s; }
    }

    // Near-tie: resolve with exact fp64 distances (true argmin, first-min tie rule).
    // EPS = 1e-2 on the score scale is ~300x the fp32 accumulation noise bound,
    // so the true argmin is always inside the near-tie set when this triggers.
    if (s1 - s2 <= 1e-2f) {
        double best = 1e300;
        int bi = 0;
        for (int k = 0; k < KK; ++k) {
            const float* wk = weight + k * DD;
            double a0 = 0.0, a1 = 0.0;
            #pragma unroll
            for (int d = 0; d < DD; d += 2) {
                double e0 = (double)xr[d]     - (double)wk[d];
                double e1 = (double)xr[d + 1] - (double)wk[d + 1];
                a0 = fma(e0, e0, a0);
                a1 = fma(e1, e1, a1);
            }
            const double dist = a0 + a1;
            if (dist < best) { best = dist; bi = k; }  // strict <: first min wins
        }
        k1 = bi;
    }

    // Write quantized: out[b,d,t] = weight[k1,d]; coalesced across lanes per d.
    const float* wb = weight + k1 * DD;
    float* qp = out + (size_t)b * DD * TT + t;
    #pragma unroll
    for (int d = 0; d < DD; ++d) qp[(size_t)d * TT] = wb[d];

    // Indices appended after quantized, written as float values.
    out[(size_t)BB * DD * TT + (size_t)b * TT + t] = (float)k1;
}

extern "C" void kernel_launch(void* const* d_in, const int* in_sizes, int n_in,
                              void* d_out, int out_size, void* d_ws, size_t ws_size,
                              hipStream_t stream) {
    const float* x      = (const float*)d_in[0];  // [32, 64, 4096] fp32
    const float* weight = (const float*)d_in[1];  // [1024, 64] fp32
    float* out = (float*)d_out;                   // 8388608 + 131072 floats

    const int total_points = BB * TT;             // 131072
    const int block = 256;
    const int grid  = total_points / block;       // 512
    vq_argmin_kernel<<<grid, block, 0, stream>>>(x, weight, out);
}

// Round 3
// 243.428 us; speedup vs baseline: 10.4309x; 10.4309x over previous
//
#include <hip/hip_runtime.h>

// VQ codebook assign: argmin_k ||x - w_k||^2 = argmax_k (x.w_k - 0.5||w_k||^2)
// GEMM formulation on matrix cores: S = X[N,64] @ W^T[64,K] via 3-pass bf16
// split (xh*wh + xh*wl + xl*wh), bias preloaded in MFMA C-in, per-lane top-2
// tracking, exact fp64 re-scan for near-ties (gap <= 1/64).
//
// Block: 256 thr = 4 waves; 128 points (one b, 128 consecutive t).
// Wave: 32 points (2 point-tiles of 16). K streamed in 32-code chunks.
// MFMA: 16x16x32 bf16. A = codes (rows), B = points (cols).
//   A/B frag: lane&15 = row/col, k = 8*(lane>>4)+e (8 contiguous k).
//   C/D:      col = lane&15 (point), row = (lane>>4)*4 + reg (code).

#define BB 32
#define DD 64
#define TT 4096
#define KK 1024
#define EPS_GAP 0.015625f  // 1/64: ~9x the bf16-split+fp32-accum error bound

typedef __attribute__((ext_vector_type(8))) short short8;
typedef __attribute__((ext_vector_type(4))) float f32x4;

__device__ __forceinline__ unsigned short f32_to_bf16_rne(float f) {
    union { float f; unsigned int u; } v; v.f = f;
    unsigned int u = v.u;
    u += 0x7fffu + ((u >> 16) & 1u);   // round-to-nearest-even
    return (unsigned short)(u >> 16);
}
__device__ __forceinline__ float bf16_bits_to_f32(unsigned short h) {
    union { unsigned int u; float f; } v; v.u = ((unsigned int)h) << 16;
    return v.f;
}

__global__ __launch_bounds__(256, 4) void vq_mfma_kernel(
    const float* __restrict__ x,       // [B, D, T]
    const float* __restrict__ weight,  // [K, D]
    float* __restrict__ out)           // quantized [B,D,T] then indices [B,T] (as float)
{
    __shared__ __align__(16) float s_wn[KK];        // -0.5*||w_k||^2
    __shared__ int s_k1[128];
    __shared__ __align__(16) char s_mem[34816];     // union: xs [128][68] f32  |  w-chunk bf16

    float* xs  = (float*)s_mem;                     // [128][68] fp32 (row pad: +4 -> 272B = 17*16)
    short* whi = (short*)s_mem;                     // [32][72] bf16 hi (row 144B = 9*16)
    short* wlo = (short*)(s_mem + 4608);            // [32][72] bf16 lo

    const int tid  = threadIdx.x;
    const int lane = tid & 63;
    const int wv   = tid >> 6;                      // wave 0..3
    const int blk  = blockIdx.x;
    const int b    = blk >> 5;                      // 32 t-tiles per batch
    const int t0   = (blk & 31) << 7;               // *128

    // ---- bias: -0.5*||w_k||^2 (each thread: 4 codebook rows) ----
    #pragma unroll
    for (int i = 0; i < 4; ++i) {
        const int k = tid * 4 + i;
        const float4* wp = (const float4*)(weight + (size_t)k * DD);
        float s = 0.f;
        #pragma unroll
        for (int j = 0; j < 16; ++j) {
            float4 v = wp[j];
            s += v.x * v.x + v.y * v.y + v.z * v.z + v.w * v.w;
        }
        s_wn[k] = -0.5f * s;
    }

    // ---- stage x tile transposed: xs[pt][d] (coalesced global reads) ----
    {
        const float* xb = x + (size_t)b * DD * TT + t0;
        for (int q = 0; q < 32; ++q) {
            int id = q * 256 + tid;
            int d = id >> 7, tl = id & 127;
            xs[tl * 68 + d] = xb[(size_t)d * TT + tl];
        }
    }
    __syncthreads();

    // ---- extract B-frags (points) hi/lo into registers, kept for whole K ----
    short8 Bh[2][2], Bl[2][2];                      // [pt-tile][kstep]
    {
        const int col = lane & 15, kg = lane >> 4;
        #pragma unroll
        for (int p = 0; p < 2; ++p) {
            const int pt = wv * 32 + p * 16 + col;
            #pragma unroll
            for (int ks = 0; ks < 2; ++ks) {
                const int dbase = ks * 32 + kg * 8;
                const float* src = &xs[pt * 68 + dbase];
                float4 f0 = *(const float4*)(src);
                float4 f1 = *(const float4*)(src + 4);
                float fv[8] = {f0.x, f0.y, f0.z, f0.w, f1.x, f1.y, f1.z, f1.w};
                short8 hb, lb;
                #pragma unroll
                for (int e = 0; e < 8; ++e) {
                    unsigned short hs = f32_to_bf16_rne(fv[e]);
                    float lof = fv[e] - bf16_bits_to_f32(hs);
                    hb[e] = (short)hs;
                    lb[e] = (short)f32_to_bf16_rne(lof);
                }
                Bh[p][ks] = hb; Bl[p][ks] = lb;
            }
        }
    }
    __syncthreads();   // xs dead; s_mem becomes w-chunk buffer

    // ---- K loop: 32 chunks of 32 codes ----
    float s1[2] = {-1e30f, -1e30f}, s2[2] = {-1e30f, -1e30f};
    int   k1[2] = {0, 0};
    const int kg = lane >> 4, col = lane & 15;

    for (int kc = 0; kc < 32; ++kc) {
        // stage w chunk -> bf16 hi/lo in LDS (each thread: 8 contiguous d of one code)
        {
            const int code = tid >> 3;
            const int dbase = (tid & 7) * 8;
            const float* src = weight + (size_t)(kc * 32 + code) * DD + dbase;
            float4 f0 = *(const float4*)src;
            float4 f1 = *(const float4*)(src + 4);
            float fv[8] = {f0.x, f0.y, f0.z, f0.w, f1.x, f1.y, f1.z, f1.w};
            short8 hb, lb;
            #pragma unroll
            for (int e = 0; e < 8; ++e) {
                unsigned short hs = f32_to_bf16_rne(fv[e]);
                float lof = fv[e] - bf16_bits_to_f32(hs);
                hb[e] = (short)hs;
                lb[e] = (short)f32_to_bf16_rne(lof);
            }
            *(short8*)&whi[code * 72 + dbase] = hb;
            *(short8*)&wlo[code * 72 + dbase] = lb;
        }
        __syncthreads();

        // acc init = bias for this chunk's codes (C row = code)
        f32x4 acc[2][2];                            // [code-tile][pt-tile]
        #pragma unroll
        for (int c = 0; c < 2; ++c) {
            f32x4 bias = *(const f32x4*)&s_wn[kc * 32 + c * 16 + kg * 4];
            acc[c][0] = bias; acc[c][1] = bias;
        }

        // MFMA: 2 ksteps x 2 code-tiles x 2 pt-tiles x 3 split passes
        #pragma unroll
        for (int ks = 0; ks < 2; ++ks) {
            #pragma unroll
            for (int c = 0; c < 2; ++c) {
                const int code = c * 16 + col;
                const int dbase = ks * 32 + kg * 8;
                short8 Ah = *(const short8*)&whi[code * 72 + dbase];
                short8 Al = *(const short8*)&wlo[code * 72 + dbase];
                #pragma unroll
                for (int p = 0; p < 2; ++p) {
                    acc[c][p] = __builtin_amdgcn_mfma_f32_16x16x32_bf16(Ah, Bh[p][ks], acc[c][p], 0, 0, 0);
                    acc[c][p] = __builtin_amdgcn_mfma_f32_16x16x32_bf16(Ah, Bl[p][ks], acc[c][p], 0, 0, 0);
                    acc[c][p] = __builtin_amdgcn_mfma_f32_16x16x32_bf16(Al, Bh[p][ks], acc[c][p], 0, 0, 0);
                }
            }
        }

        // per-lane top-2 update over this chunk's 16 scores (codes increasing: first-wins)
        #pragma unroll
        for (int p = 0; p < 2; ++p)
            #pragma unroll
            for (int c = 0; c < 2; ++c)
                #pragma unroll
                for (int r = 0; r < 4; ++r) {
                    const float s = acc[c][p][r];
                    const int code = kc * 32 + c * 16 + kg * 4 + r;
                    const float ns2 = fmaxf(fminf(s, s1[p]), s2[p]);  // med3(s, s1_old, s2_old)
                    if (s > s1[p]) { k1[p] = code; s1[p] = s; }
                    s2[p] = ns2;
                }
        __syncthreads();   // protect whi/wlo before next stage
    }

    // ---- cross-lane merge (lanes l, l^16, l^32, l^48 share a point column) ----
    #pragma unroll
    for (int p = 0; p < 2; ++p) {
        #pragma unroll
        for (int off = 16; off < 64; off <<= 1) {
            float o1 = __shfl_xor(s1[p], off, 64);
            float o2 = __shfl_xor(s2[p], off, 64);
            int   ok = __shfl_xor(k1[p], off, 64);
            bool takeo = (o1 > s1[p]) || (o1 == s1[p] && ok < k1[p]);
            float ns2 = fmaxf(fminf(s1[p], o1), fmaxf(s2[p], o2));
            if (takeo) { s1[p] = o1; k1[p] = ok; }
            s2[p] = ns2;
        }

        // near-tie: exact fp64 full re-scan (first-min tie rule = true argmin)
        unsigned long long m = __ballot((s1[p] - s2[p]) <= EPS_GAP) & 0xFFFFull;
        while (m) {
            const int ptl = __ffsll(m) - 1; m &= m - 1;
            const int t = t0 + wv * 32 + p * 16 + ptl;
            const float* xp = x + (size_t)b * DD * TT + t;
            double bd = 1e300; int bk = 0;
            for (int j = 0; j < 16; ++j) {
                const int k = lane + 64 * j;
                const float* wk = weight + (size_t)k * DD;
                double a0 = 0.0, a1 = 0.0;
                #pragma unroll
                for (int d = 0; d < DD; d += 2) {
                    double e0 = (double)xp[(size_t)d * TT]       - (double)wk[d];
                    double e1 = (double)xp[(size_t)(d + 1) * TT] - (double)wk[d + 1];
                    a0 = fma(e0, e0, a0);
                    a1 = fma(e1, e1, a1);
                }
                const double dist = a0 + a1;
                if (dist < bd || (dist == bd && k < bk)) { bd = dist; bk = k; }
            }
            #pragma unroll
            for (int off = 1; off < 64; off <<= 1) {
                double od = __shfl_xor(bd, off, 64);
                int    okk = __shfl_xor(bk, off, 64);
                if (od < bd || (od == bd && okk < bk)) { bd = od; bk = okk; }
            }
            if ((lane & 15) == ptl) k1[p] = bk;
        }

        if (lane < 16) s_k1[wv * 32 + p * 16 + lane] = k1[p];
    }
    __syncthreads();

    // ---- epilogue ----
    // indices (as float), coalesced
    if (tid < 128)
        out[(size_t)BB * DD * TT + (size_t)b * TT + t0 + tid] = (float)s_k1[tid];

    // quantized: thread = (pt = tid&127, half = tid>>7 covering 32 d's)
    {
        const int pt = tid & 127;
        const int half = tid >> 7;
        const int k = s_k1[pt];
        const float4* wr = (const float4*)(weight + (size_t)k * DD + half * 32);
        float* op = out + ((size_t)b * DD + half * 32) * TT + t0 + pt;
        #pragma unroll
        for (int jq = 0; jq < 8; ++jq) {
            float4 v = wr[jq];
            op[(size_t)(jq * 4 + 0) * TT] = v.x;
            op[(size_t)(jq * 4 + 1) * TT] = v.y;
            op[(size_t)(jq * 4 + 2) * TT] = v.z;
            op[(size_t)(jq * 4 + 3) * TT] = v.w;
        }
    }
}

extern "C" void kernel_launch(void* const* d_in, const int* in_sizes, int n_in,
                              void* d_out, int out_size, void* d_ws, size_t ws_size,
                              hipStream_t stream) {
    const float* x      = (const float*)d_in[0];  // [32, 64, 4096] fp32
    const float* weight = (const float*)d_in[1];  // [1024, 64] fp32
    float* out = (float*)d_out;                   // 8388608 + 131072 floats

    const int grid = (BB * TT) / 128;             // 1024 blocks, 128 points each
    vq_mfma_kernel<<<grid, 256, 0, stream>>>(x, weight, out);
}

// Round 4
// 166.955 us; speedup vs baseline: 15.2088x; 1.4580x over previous
//
#include <hip/hip_runtime.h>

// VQ codebook assign: argmin_k ||x-w_k||^2 = argmax_k (x.w_k - 0.5||w_k||^2)
// Round 4: barrier-free, LDS-free main loop.
//  - prep kernel: weight -> bf16 hi/lo split, PRE-SWIZZLED into MFMA A-frag
//    order (rec[r][lane] 16B each, r = (kc*2+ks)*2+c), + bias = -0.5||w||^2.
//    256KB + 4KB in d_ws, L2-resident.
//  - main kernel: x -> B-frags directly from global (no LDS transpose),
//    K-loop = 8 coalesced L2 loads + 2 bias loads + 24 MFMA + top-2 update.
//    No __syncthreads anywhere; epilogue index exchange via __shfl.
//  - exactness: fp32 top-2 + fp64 re-scan when gap <= 1/64 (proven round 2/3).

#define BB 32
#define DD 64
#define TT 4096
#define KK 1024
#define EPS_GAP 0.015625f

typedef __attribute__((ext_vector_type(8))) short short8;
typedef __attribute__((ext_vector_type(4))) float f32x4;

static __device__ __forceinline__ unsigned short f32_to_bf16_rne(float f) {
    union { float f; unsigned int u; } v; v.f = f;
    unsigned int u = v.u;
    u += 0x7fffu + ((u >> 16) & 1u);
    return (unsigned short)(u >> 16);
}
static __device__ __forceinline__ float bf16_bits_to_f32(unsigned short h) {
    union { unsigned int u; float f; } v; v.u = ((unsigned int)h) << 16;
    return v.f;
}

// ---- prep: weight -> swizzled bf16 hi/lo records + bias ----
__global__ __launch_bounds__(256) void vq_prep(
    const float* __restrict__ w, float* __restrict__ bias, unsigned short* __restrict__ rec)
{
    const int g    = blockIdx.x * 256 + threadIdx.x;   // 0..8191
    const int lane = g & 63;
    const int r    = g >> 6;                           // record 0..127
    const int kc   = r >> 2, ks = (r >> 1) & 1, c = r & 1;
    const int code  = kc * 32 + c * 16 + (lane & 15);
    const int dbase = ks * 32 + (lane >> 4) * 8;

    const float* src = w + (size_t)code * DD + dbase;
    float4 f0 = *(const float4*)src;
    float4 f1 = *(const float4*)(src + 4);
    float fv[8] = {f0.x, f0.y, f0.z, f0.w, f1.x, f1.y, f1.z, f1.w};
    short8 hb, lb;
    #pragma unroll
    for (int e = 0; e < 8; ++e) {
        unsigned short hs = f32_to_bf16_rne(fv[e]);
        hb[e] = (short)hs;
        lb[e] = (short)f32_to_bf16_rne(fv[e] - bf16_bits_to_f32(hs));
    }
    *(short8*)(rec + (size_t)r * 1024 + lane * 8)       = hb;  // hi
    *(short8*)(rec + (size_t)r * 1024 + 512 + lane * 8) = lb;  // lo

    if (g < KK) {
        const float4* wp = (const float4*)(w + (size_t)g * DD);
        float s = 0.f;
        #pragma unroll
        for (int j = 0; j < 16; ++j) {
            float4 v = wp[j];
            s += v.x * v.x + v.y * v.y + v.z * v.z + v.w * v.w;
        }
        bias[g] = -0.5f * s;
    }
}

// ---- main ----
__global__ __launch_bounds__(256, 3) void vq_main(
    const float* __restrict__ x,            // [B, D, T]
    const float* __restrict__ weight,       // [K, D] fp32 (epilogue gather)
    const float* __restrict__ bias,         // [K]
    const unsigned short* __restrict__ rec, // swizzled bf16 hi/lo A-frags
    float* __restrict__ out)                // quantized [B,D,T] then indices [B,T]
{
    const int tid  = threadIdx.x;
    const int lane = tid & 63;
    const int wv   = tid >> 6;
    const int b    = blockIdx.x >> 5;
    const int t0   = (blockIdx.x & 31) << 7;
    const int col  = lane & 15, kg = lane >> 4;

    // ---- x -> B-frags (hi/lo) straight from global ----
    short8 Bh[2][2], Bl[2][2];              // [pt-tile][kstep]
    {
        const float* xb = x + (size_t)b * DD * TT + t0 + wv * 32 + col;
        #pragma unroll
        for (int p = 0; p < 2; ++p)
            #pragma unroll
            for (int ks = 0; ks < 2; ++ks) {
                float fv[8];
                #pragma unroll
                for (int e = 0; e < 8; ++e)
                    fv[e] = xb[(size_t)(ks * 32 + kg * 8 + e) * TT + p * 16];
                short8 hb, lb;
                #pragma unroll
                for (int e = 0; e < 8; ++e) {
                    unsigned short hs = f32_to_bf16_rne(fv[e]);
                    hb[e] = (short)hs;
                    lb[e] = (short)f32_to_bf16_rne(fv[e] - bf16_bits_to_f32(hs));
                }
                Bh[p][ks] = hb; Bl[p][ks] = lb;
            }
    }

    // ---- K loop: 32 chunks of 32 codes, barrier-free ----
    float s1[2] = {-1e30f, -1e30f}, s2[2] = {-1e30f, -1e30f};
    int   k1[2] = {0, 0};

    for (int kc = 0; kc < 32; ++kc) {
        short8 Ah[2][2], Al[2][2];          // [ks][c-tile]
        #pragma unroll
        for (int ks = 0; ks < 2; ++ks)
            #pragma unroll
            for (int c = 0; c < 2; ++c) {
                const unsigned short* p0 = rec + (size_t)((kc * 2 + ks) * 2 + c) * 1024 + lane * 8;
                Ah[ks][c] = *(const short8*)p0;
                Al[ks][c] = *(const short8*)(p0 + 512);
            }

        f32x4 acc[2][2];                    // [c-tile][pt-tile]
        #pragma unroll
        for (int c = 0; c < 2; ++c) {
            f32x4 bv = *(const f32x4*)(bias + kc * 32 + c * 16 + kg * 4);
            acc[c][0] = bv; acc[c][1] = bv;
        }

        #pragma unroll
        for (int ks = 0; ks < 2; ++ks)
            #pragma unroll
            for (int c = 0; c < 2; ++c)
                #pragma unroll
                for (int p = 0; p < 2; ++p) {
                    acc[c][p] = __builtin_amdgcn_mfma_f32_16x16x32_bf16(Ah[ks][c], Bh[p][ks], acc[c][p], 0, 0, 0);
                    acc[c][p] = __builtin_amdgcn_mfma_f32_16x16x32_bf16(Ah[ks][c], Bl[p][ks], acc[c][p], 0, 0, 0);
                    acc[c][p] = __builtin_amdgcn_mfma_f32_16x16x32_bf16(Al[ks][c], Bh[p][ks], acc[c][p], 0, 0, 0);
                }

        // top-2 update (codes ascend per lane: first-wins argmin tie rule)
        #pragma unroll
        for (int p = 0; p < 2; ++p)
            #pragma unroll
            for (int c = 0; c < 2; ++c)
                #pragma unroll
                for (int r = 0; r < 4; ++r) {
                    const float s = acc[c][p][r];
                    const int code = kc * 32 + c * 16 + kg * 4 + r;
                    const float ns2 = fmaxf(fminf(s, s1[p]), s2[p]);
                    if (s > s1[p]) { k1[p] = code; s1[p] = s; }
                    s2[p] = ns2;
                }
    }

    // ---- cross-lane merge (lanes l, l^16, l^32, l^48 share a point) ----
    #pragma unroll
    for (int p = 0; p < 2; ++p) {
        #pragma unroll
        for (int off = 16; off < 64; off <<= 1) {
            float o1 = __shfl_xor(s1[p], off, 64);
            float o2 = __shfl_xor(s2[p], off, 64);
            int   ok = __shfl_xor(k1[p], off, 64);
            bool takeo = (o1 > s1[p]) || (o1 == s1[p] && ok < k1[p]);
            float ns2 = fmaxf(fminf(s1[p], o1), fmaxf(s2[p], o2));
            if (takeo) { s1[p] = o1; k1[p] = ok; }
            s2[p] = ns2;
        }

        // near-tie: exact fp64 full re-scan (true argmin, first-min tie rule)
        unsigned long long m = __ballot((s1[p] - s2[p]) <= EPS_GAP) & 0xFFFFull;
        while (m) {
            const int ptt = __ffsll(m) - 1; m &= m - 1;
            const int t = t0 + wv * 32 + p * 16 + ptt;
            const float* xp = x + (size_t)b * DD * TT + t;
            double bd = 1e300; int bk = 0;
            for (int j = 0; j < 16; ++j) {
                const int k = lane + 64 * j;
                const float* wk = weight + (size_t)k * DD;
                double a0 = 0.0, a1 = 0.0;
                #pragma unroll
                for (int d = 0; d < DD; d += 2) {
                    double e0 = (double)xp[(size_t)d * TT]       - (double)wk[d];
                    double e1 = (double)xp[(size_t)(d + 1) * TT] - (double)wk[d + 1];
                    a0 = fma(e0, e0, a0);
                    a1 = fma(e1, e1, a1);
                }
                const double dist = a0 + a1;
                if (dist < bd || (dist == bd && k < bk)) { bd = dist; bk = k; }
            }
            #pragma unroll
            for (int off = 1; off < 64; off <<= 1) {
                double od = __shfl_xor(bd, off, 64);
                int    okk = __shfl_xor(bk, off, 64);
                if (od < bd || (od == bd && okk < bk)) { bd = od; bk = okk; }
            }
            k1[p] = ((lane & 15) == ptt) ? bk : k1[p];
        }
    }

    // ---- per-wave epilogue (no LDS): distribute indices via shfl ----
    const int ptl = lane & 31;              // point within wave
    const int v0 = k1[0], v1 = k1[1];
    const int q0 = __shfl(v0, ptl & 15, 64);
    const int q1 = __shfl(v1, ptl & 15, 64);
    const int kq = (ptl < 16) ? q0 : q1;

    // indices (as float), 32 per wave, coalesced
    if (lane < 32)
        out[(size_t)BB * DD * TT + (size_t)b * TT + t0 + wv * 32 + lane] = (float)kq;

    // quantized: lane -> (pt = wv*32+ptl, half = lane>>5 covering 32 d's)
    {
        const int half = lane >> 5;
        const float4* wr = (const float4*)(weight + (size_t)kq * DD + half * 32);
        float* op = out + ((size_t)b * DD + half * 32) * TT + t0 + wv * 32 + ptl;
        #pragma unroll
        for (int jq = 0; jq < 8; ++jq) {
            float4 v = wr[jq];
            op[(size_t)(jq * 4 + 0) * TT] = v.x;
            op[(size_t)(jq * 4 + 1) * TT] = v.y;
            op[(size_t)(jq * 4 + 2) * TT] = v.z;
            op[(size_t)(jq * 4 + 3) * TT] = v.w;
        }
    }
}

extern "C" void kernel_launch(void* const* d_in, const int* in_sizes, int n_in,
                              void* d_out, int out_size, void* d_ws, size_t ws_size,
                              hipStream_t stream) {
    const float* x      = (const float*)d_in[0];  // [32, 64, 4096] fp32
    const float* weight = (const float*)d_in[1];  // [1024, 64] fp32
    float* out = (float*)d_out;

    float* bias        = (float*)d_ws;                            // 4 KB
    unsigned short* rec = (unsigned short*)((char*)d_ws + 4096);  // 256 KB

    vq_prep<<<32, 256, 0, stream>>>(weight, bias, rec);
    vq_main<<<(BB * TT) / 128, 256, 0, stream>>>(x, weight, bias, rec, out);
}

// Round 5
// 101.495 us; speedup vs baseline: 25.0177x; 1.6449x over previous
//
#include <hip/hip_runtime.h>

// VQ codebook assign: argmin_k ||x-w_k||^2 = argmax_k (x.w_k - 0.5||w_k||^2)
// Round 5:
//  - main loop: 64 points/wave (4 pt-tiles), 2-stage A-frag prefetch, no LDS,
//    no barriers. rec L2 traffic halved vs round 4.
//  - exact path DECOUPLED: near-ties (gap<=1/128) pushed to atomic worklist;
//    vq_fixup (1 block/point, coalesced fp64 full scan) overwrites results.
//    Inline slow fallback only on worklist overflow (practically never).
//
// ws layout: bias[1024]f32 @0 (4KB) | rec bf16 hi/lo @4096 (256KB)
//            | cnt(int) @266240 | list @266256

#define BB 32
#define DD 64
#define TT 4096
#define KK 1024
#define EPS_GAP 0.0078125f   // 1/128; worst-case bf16-split gap error ~1.6e-3

#define REC_OFF  4096
#define CNT_OFF  266240
#define LIST_OFF 266256

typedef __attribute__((ext_vector_type(8))) short short8;
typedef __attribute__((ext_vector_type(4))) float f32x4;

static __device__ __forceinline__ unsigned short f32_to_bf16_rne(float f) {
    union { float f; unsigned int u; } v; v.f = f;
    unsigned int u = v.u;
    u += 0x7fffu + ((u >> 16) & 1u);
    return (unsigned short)(u >> 16);
}
static __device__ __forceinline__ float bf16_bits_to_f32(unsigned short h) {
    union { unsigned int u; float f; } v; v.u = ((unsigned int)h) << 16;
    return v.f;
}

// ---- prep: weight -> swizzled bf16 hi/lo A-frag records + bias; reset cnt ----
__global__ __launch_bounds__(256) void vq_prep(
    const float* __restrict__ w, float* __restrict__ bias,
    unsigned short* __restrict__ rec, int* __restrict__ cnt)
{
    const int g    = blockIdx.x * 256 + threadIdx.x;   // 0..8191
    if (g == 0) *cnt = 0;
    const int lane = g & 63;
    const int r    = g >> 6;                           // record 0..127
    const int kc   = r >> 2, ks = (r >> 1) & 1, c = r & 1;
    const int code  = kc * 32 + c * 16 + (lane & 15);
    const int dbase = ks * 32 + (lane >> 4) * 8;

    const float* src = w + (size_t)code * DD + dbase;
    float4 f0 = *(const float4*)src;
    float4 f1 = *(const float4*)(src + 4);
    float fv[8] = {f0.x, f0.y, f0.z, f0.w, f1.x, f1.y, f1.z, f1.w};
    short8 hb, lb;
    #pragma unroll
    for (int e = 0; e < 8; ++e) {
        unsigned short hs = f32_to_bf16_rne(fv[e]);
        hb[e] = (short)hs;
        lb[e] = (short)f32_to_bf16_rne(fv[e] - bf16_bits_to_f32(hs));
    }
    *(short8*)(rec + (size_t)r * 1024 + lane * 8)       = hb;
    *(short8*)(rec + (size_t)r * 1024 + 512 + lane * 8) = lb;

    if (g < KK) {
        const float4* wp = (const float4*)(w + (size_t)g * DD);
        float s = 0.f;
        #pragma unroll
        for (int j = 0; j < 16; ++j) {
            float4 v = wp[j];
            s += v.x * v.x + v.y * v.y + v.z * v.z + v.w * v.w;
        }
        bias[g] = -0.5f * s;
    }
}

// ---- main: 4 waves x 64 points per block ----
__global__ __launch_bounds__(256, 2) void vq_main(
    const float* __restrict__ x,
    const float* __restrict__ weight,
    const float* __restrict__ bias,
    const unsigned short* __restrict__ rec,
    int* __restrict__ cnt, int* __restrict__ list, int cap,
    float* __restrict__ out)
{
    const int tid  = threadIdx.x;
    const int lane = tid & 63;
    const int wv   = tid >> 6;
    const int b    = blockIdx.x >> 4;                  // 16 tiles of 256 pts per batch
    const int t0   = (blockIdx.x & 15) << 8;
    const int col  = lane & 15, kg = lane >> 4;

    // x -> B-frags (hi/lo) straight from global
    short8 Bh[4][2], Bl[4][2];                         // [pt-tile][kstep]
    {
        const float* xb = x + (size_t)b * DD * TT + t0 + wv * 64 + col;
        #pragma unroll
        for (int p = 0; p < 4; ++p)
            #pragma unroll
            for (int ks = 0; ks < 2; ++ks) {
                float fv[8];
                #pragma unroll
                for (int e = 0; e < 8; ++e)
                    fv[e] = xb[(size_t)(ks * 32 + kg * 8 + e) * TT + p * 16];
                short8 hb, lb;
                #pragma unroll
                for (int e = 0; e < 8; ++e) {
                    unsigned short hs = f32_to_bf16_rne(fv[e]);
                    hb[e] = (short)hs;
                    lb[e] = (short)f32_to_bf16_rne(fv[e] - bf16_bits_to_f32(hs));
                }
                Bh[p][ks] = hb; Bl[p][ks] = lb;
            }
    }

    float s1[4] = {-1e30f, -1e30f, -1e30f, -1e30f};
    float s2[4] = {-1e30f, -1e30f, -1e30f, -1e30f};
    int   k1[4] = {0, 0, 0, 0};

    auto loadA = [&](int kc, short8 (*Ah)[2], short8 (*Al)[2]) {
        #pragma unroll
        for (int ks = 0; ks < 2; ++ks)
            #pragma unroll
            for (int c = 0; c < 2; ++c) {
                const unsigned short* p0 = rec + (size_t)((kc * 2 + ks) * 2 + c) * 1024 + lane * 8;
                Ah[ks][c] = *(const short8*)p0;
                Al[ks][c] = *(const short8*)(p0 + 512);
            }
    };
    auto compute = [&](int kc, short8 (*Ah)[2], short8 (*Al)[2]) {
        f32x4 acc[2][4];                               // [c-tile][pt-tile]
        #pragma unroll
        for (int c = 0; c < 2; ++c) {
            f32x4 bv = *(const f32x4*)(bias + kc * 32 + c * 16 + kg * 4);
            #pragma unroll
            for (int p = 0; p < 4; ++p) acc[c][p] = bv;
        }
        #pragma unroll
        for (int ks = 0; ks < 2; ++ks)
            #pragma unroll
            for (int c = 0; c < 2; ++c)
                #pragma unroll
                for (int p = 0; p < 4; ++p) {
                    acc[c][p] = __builtin_amdgcn_mfma_f32_16x16x32_bf16(Ah[ks][c], Bh[p][ks], acc[c][p], 0, 0, 0);
                    acc[c][p] = __builtin_amdgcn_mfma_f32_16x16x32_bf16(Ah[ks][c], Bl[p][ks], acc[c][p], 0, 0, 0);
                    acc[c][p] = __builtin_amdgcn_mfma_f32_16x16x32_bf16(Al[ks][c], Bh[p][ks], acc[c][p], 0, 0, 0);
                }
        #pragma unroll
        for (int p = 0; p < 4; ++p)
            #pragma unroll
            for (int c = 0; c < 2; ++c)
                #pragma unroll
                for (int r = 0; r < 4; ++r) {
                    const float s = acc[c][p][r];
                    const int code = kc * 32 + c * 16 + kg * 4 + r;
                    const float ns2 = fmaxf(fminf(s, s1[p]), s2[p]);
                    if (s > s1[p]) { k1[p] = code; s1[p] = s; }
                    s2[p] = ns2;
                }
    };

    // K loop: 32 chunks, 2-stage prefetch pipeline
    short8 A0h[2][2], A0l[2][2], A1h[2][2], A1l[2][2];
    loadA(0, A0h, A0l);
    for (int kc = 0; kc < 32; kc += 2) {
        loadA(kc + 1, A1h, A1l);
        compute(kc, A0h, A0l);
        if (kc + 2 < 32) loadA(kc + 2, A0h, A0l);
        compute(kc + 1, A1h, A1l);
    }

    // cross-lane merge: lanes l, l^16, l^32, l^48 share a point
    #pragma unroll
    for (int p = 0; p < 4; ++p) {
        #pragma unroll
        for (int off = 16; off < 64; off <<= 1) {
            float o1 = __shfl_xor(s1[p], off, 64);
            float o2 = __shfl_xor(s2[p], off, 64);
            int   ok = __shfl_xor(k1[p], off, 64);
            bool takeo = (o1 > s1[p]) || (o1 == s1[p] && ok < k1[p]);
            float ns2 = fmaxf(fminf(s1[p], o1), fmaxf(s2[p], o2));
            if (takeo) { s1[p] = o1; k1[p] = ok; }
            s2[p] = ns2;
        }

        // near-tie: push to worklist (fixup kernel resolves exactly)
        bool flag = (lane < 16) && ((s1[p] - s2[p]) <= EPS_GAP);
        int slot = -1;
        if (flag) slot = atomicAdd(cnt, 1);
        if (flag && slot < cap)
            list[slot] = b * TT + t0 + wv * 64 + p * 16 + lane;

        // overflow fallback: inline exact fp64 re-scan (practically never)
        unsigned long long m = __ballot(flag && slot >= cap);
        while (m) {
            const int ptt = __ffsll(m) - 1; m &= m - 1;
            const int t = t0 + wv * 64 + p * 16 + ptt;
            const float* xp = x + (size_t)b * DD * TT + t;
            double bd = 1e300; int bk = 0;
            for (int j = 0; j < 16; ++j) {
                const int k = lane + 64 * j;
                const float* wk = weight + (size_t)k * DD;
                double a0 = 0.0, a1 = 0.0;
                #pragma unroll
                for (int d = 0; d < DD; d += 2) {
                    double e0 = (double)xp[(size_t)d * TT]       - (double)wk[d];
                    double e1 = (double)xp[(size_t)(d + 1) * TT] - (double)wk[d + 1];
                    a0 = fma(e0, e0, a0);
                    a1 = fma(e1, e1, a1);
                }
                const double dist = a0 + a1;
                if (dist < bd || (dist == bd && k < bk)) { bd = dist; bk = k; }
            }
            #pragma unroll
            for (int off = 1; off < 64; off <<= 1) {
                double od = __shfl_xor(bd, off, 64);
                int    okk = __shfl_xor(bk, off, 64);
                if (od < bd || (od == bd && okk < bk)) { bd = od; bk = okk; }
            }
            if ((lane & 15) == ptt) k1[p] = bk;
        }
    }

    // epilogue: distribute indices via shfl; lane owns point ptl = lane
    const int q0 = __shfl(k1[0], lane & 15, 64);
    const int q1 = __shfl(k1[1], lane & 15, 64);
    const int q2 = __shfl(k1[2], lane & 15, 64);
    const int q3 = __shfl(k1[3], lane & 15, 64);
    const int hp = lane >> 4;
    const int kq = (hp == 0) ? q0 : (hp == 1) ? q1 : (hp == 2) ? q2 : q3;

    const int t = t0 + wv * 64 + lane;
    out[(size_t)BB * DD * TT + (size_t)b * TT + t] = (float)kq;

    // quantized: lane writes its point's full column (64 d), coalesced across lanes
    {
        const float4* wr = (const float4*)(weight + (size_t)kq * DD);
        float* op = out + (size_t)b * DD * TT + t;
        #pragma unroll
        for (int jq = 0; jq < 16; ++jq) {
            float4 v = wr[jq];
            op[(size_t)(jq * 4 + 0) * TT] = v.x;
            op[(size_t)(jq * 4 + 1) * TT] = v.y;
            op[(size_t)(jq * 4 + 2) * TT] = v.z;
            op[(size_t)(jq * 4 + 3) * TT] = v.w;
        }
    }
}

// ---- fixup: one block per flagged point, coalesced exact fp64 full scan ----
__global__ __launch_bounds__(256) void vq_fixup(
    const float* __restrict__ x, const float* __restrict__ w,
    const int* __restrict__ cnt, const int* __restrict__ list, int cap,
    float* __restrict__ out)
{
    __shared__ double sd[4];
    __shared__ int    sk[4];
    int n = *cnt; if (n > cap) n = cap;

    for (int i = blockIdx.x; i < n; i += gridDim.x) {
        const int g = list[i];
        const int b = g >> 12;             // TT = 4096
        const int t = g & (TT - 1);
        const float* xp = x + (size_t)b * DD * TT + t;

        const int quarter = threadIdx.x & 3;       // 16 d's each
        const int cbase   = threadIdx.x >> 2;      // 0..63

        double xq[16];
        #pragma unroll
        for (int j = 0; j < 16; ++j)
            xq[j] = (double)xp[(size_t)(quarter * 16 + j) * TT];

        double bd = 1e300; int bk = 0;
        for (int it = 0; it < 16; ++it) {
            const int code = cbase + (it << 6);
            const float4* wr = (const float4*)(w + (size_t)code * DD + quarter * 16);
            double a = 0.0;
            #pragma unroll
            for (int q4 = 0; q4 < 4; ++q4) {
                float4 v = wr[q4];
                double e0 = xq[q4 * 4 + 0] - (double)v.x;
                double e1 = xq[q4 * 4 + 1] - (double)v.y;
                double e2 = xq[q4 * 4 + 2] - (double)v.z;
                double e3 = xq[q4 * 4 + 3] - (double)v.w;
                a = fma(e0, e0, a); a = fma(e1, e1, a);
                a = fma(e2, e2, a); a = fma(e3, e3, a);
            }
            a += __shfl_xor(a, 1, 64);
            a += __shfl_xor(a, 2, 64);
            if (a < bd || (a == bd && code < bk)) { bd = a; bk = code; }
        }
        #pragma unroll
        for (int off = 4; off < 64; off <<= 1) {
            double od = __shfl_xor(bd, off, 64);
            int    ok = __shfl_xor(bk, off, 64);
            if (od < bd || (od == bd && ok < bk)) { bd = od; bk = ok; }
        }
        if ((threadIdx.x & 63) == 0) { sd[threadIdx.x >> 6] = bd; sk[threadIdx.x >> 6] = bk; }
        __syncthreads();
        double fb = sd[0]; int fk = sk[0];
        #pragma unroll
        for (int wvi = 1; wvi < 4; ++wvi)
            if (sd[wvi] < fb || (sd[wvi] == fb && sk[wvi] < fk)) { fb = sd[wvi]; fk = sk[wvi]; }

        if (threadIdx.x == 0)
            out[(size_t)BB * DD * TT + g] = (float)fk;
        if (threadIdx.x < 64)
            out[(size_t)b * DD * TT + (size_t)threadIdx.x * TT + t] = w[(size_t)fk * DD + threadIdx.x];
        __syncthreads();   // sd/sk reuse
    }
}

extern "C" void kernel_launch(void* const* d_in, const int* in_sizes, int n_in,
                              void* d_out, int out_size, void* d_ws, size_t ws_size,
                              hipStream_t stream) {
    const float* x      = (const float*)d_in[0];
    const float* weight = (const float*)d_in[1];
    float* out = (float*)d_out;

    float* bias         = (float*)d_ws;
    unsigned short* rec = (unsigned short*)((char*)d_ws + REC_OFF);
    int* cnt            = (int*)((char*)d_ws + CNT_OFF);
    int* list           = (int*)((char*)d_ws + LIST_OFF);
    long long avail = (long long)ws_size - LIST_OFF;
    int cap = avail > 0 ? (int)(avail / 4) : 0;
    if (cap > BB * TT) cap = BB * TT;

    vq_prep<<<32, 256, 0, stream>>>(weight, bias, rec, cnt);
    vq_main<<<(BB * TT) / 256, 256, 0, stream>>>(x, weight, bias, rec, cnt, list, cap, out);
    vq_fixup<<<128, 256, 0, stream>>>(x, weight, cnt, list, cap, out);
}